// Round 13
// baseline (281.909 us; speedup 1.0000x reference)
//
#include <hip/hip_runtime.h>
#include <math.h>

#define BB 16
#define CC 20
#define CI 10
#define CG 256
#define CIG 128
#define HH 80
#define WW 80
#define NN 6400
#define HP 40
#define WPD 40
#define NP 1600
#define CNT (BB*NN)   // 102400

// workspace layout (float offsets)
#define OFF_THETA 0
#define OFF_PHI   (OFF_THETA + BB*CI*NN)     // 1,024,000
#define OFF_Y     (OFF_PHI + BB*CI*NP)       // 1,280,000
#define OFF_SUMY  (OFF_Y + BB*NN*CIG)       // 14,387,200
#define OFF_MYY   (OFF_SUMY + 128)
#define OFF_A     (OFF_MYY + 128*128)
#define OFF_BC    (OFF_A + 256)
#define OFF_GW16  (OFF_BC + 256)             // f16: CG*CIG halves, chunk-contig [kc][co][32]
#define OFF_WW16  (OFF_GW16 + CG*CIG/2)      // f16: [co=256][k=128] halves
#define OFF_GT    (OFF_WW16 + CG*CIG/2)      // f16: 16*128*1600 halves
#define OFF_PARTS (OFF_GT + BB*CIG*NP/2)     // fp32: [128][800] per-block channel sums
// total floats: OFF_PARTS + 128*800 = 16,177,792  (~64.7 MB)

typedef _Float16 f16x8 __attribute__((ext_vector_type(8)));
typedef float f32x4 __attribute__((ext_vector_type(4)));
typedef float f32x16 __attribute__((ext_vector_type(16)));

// ---------------- K0: weight prep: gw -> f16 chunk-contig, Ww -> f16 --------
__global__ void k0_prep(const float* __restrict__ gw,
                        const float* __restrict__ ww,
                        float* __restrict__ ws) {
    int idx = blockIdx.x * 256 + threadIdx.x;   // 0..32767
    if (idx < CG * CIG) {
        int co = idx / CG, ci = idx % CG;       // g_w[co][ci], co<128, ci<256
        _Float16* gw16 = (_Float16*)(ws + OFF_GW16);
        gw16[(ci >> 5) * (CIG * 32) + co * 32 + (ci & 31)] = (_Float16)gw[idx];
        _Float16* ww16 = (_Float16*)(ws + OFF_WW16);
        ww16[idx] = (_Float16)ww[idx];          // W_w[co=256][k=128] row-major
    }
}

// ---------------- K1a: theta conv (full res), layout (B, CI, N) --------------
__global__ __launch_bounds__(256) void k1_theta(const float* __restrict__ xc,
                                                const float* __restrict__ tw,
                                                const float* __restrict__ tb,
                                                float* __restrict__ ws) {
    __shared__ float w[CI * CC];
    __shared__ float bia[CI];
    int t = threadIdx.x;
    if (t < CI * CC) w[t] = tw[t];
    if (t < CI) bia[t] = tb[t];
    __syncthreads();
    int idx = blockIdx.x * 256 + t;     // < 102400
    int b = idx / NN, n = idx % NN;
    float acc[CI];
#pragma unroll
    for (int o = 0; o < CI; o++) acc[o] = bia[o];
#pragma unroll
    for (int c = 0; c < CC; c++) {
        float x = xc[(b * CC + c) * NN + n];
#pragma unroll
        for (int o = 0; o < CI; o++) acc[o] += w[o * CC + c] * x;
    }
#pragma unroll
    for (int o = 0; o < CI; o++) ws[OFF_THETA + (b * CI + o) * NN + n] = acc[o];
}

// ---------------- K1b: phi conv + 2x2 maxpool, layout (B, CI, NP) ------------
__global__ __launch_bounds__(256) void k1_phi(const float* __restrict__ xc,
                                              const float* __restrict__ pw,
                                              const float* __restrict__ pb,
                                              float* __restrict__ ws) {
    __shared__ float w[CI * CC];
    __shared__ float bia[CI];
    int t = threadIdx.x;
    if (t < CI * CC) w[t] = pw[t];
    if (t < CI) bia[t] = pb[t];
    __syncthreads();
    int idx = blockIdx.x * 256 + t;    // < 25600
    int b = idx / NP, mp = idx % NP;
    int hp = mp / WPD, wp = mp % WPD;
    float best[CI];
#pragma unroll
    for (int o = 0; o < CI; o++) best[o] = -1e30f;
#pragma unroll
    for (int p = 0; p < 4; p++) {
        int n = (2 * hp + (p >> 1)) * WW + 2 * wp + (p & 1);
        float acc[CI];
#pragma unroll
        for (int o = 0; o < CI; o++) acc[o] = bia[o];
#pragma unroll
        for (int c = 0; c < CC; c++) {
            float x = xc[(b * CC + c) * NN + n];
#pragma unroll
            for (int o = 0; o < CI; o++) acc[o] += w[o * CC + c] * x;
        }
#pragma unroll
        for (int o = 0; o < CI; o++) best[o] = fmaxf(best[o], acc[o]);
    }
#pragma unroll
    for (int o = 0; o < CI; o++) ws[OFF_PHI + (b * CI + o) * NP + mp] = best[o];
}

// ---------------- K2: MFMA f16 g-conv (K=256) + 2x2 maxpool -> gT f16 --------
__global__ __launch_bounds__(256) void k2_convg(const float* __restrict__ x1,
                                                const float* __restrict__ gb,
                                                float* __restrict__ ws) {
    __shared__ _Float16 smem[21760];    // 43.5 KB
    const int t = threadIdx.x;
    const int w = t >> 6, l = t & 63, h = l >> 5, ln = l & 31;
    const int bid = blockIdx.x;
    const int b = bid / 40, nb = bid % 40;
    const int n0 = nb * 160;
    const ushort* gw16 = (const ushort*)(ws + OFF_GW16);
    const float* xsrc = x1 + (size_t)b * CG * NN + n0;

    f32x16 acc[5];
#pragma unroll
    for (int j = 0; j < 5; j++)
#pragma unroll
        for (int r = 0; r < 16; r++) acc[j][r] = 0.f;

    const int bk = t >> 3, bs = t & 7;      // B-stage: k-row, n-seg(20)
    uint4 ar[2];
    float4 br[5];

#define K2_LOAD(kc)                                                              \
    {                                                                            \
        ar[0] = *(const uint4*)(gw16 + (kc) * 4096 + t * 16);                    \
        ar[1] = *(const uint4*)(gw16 + (kc) * 4096 + t * 16 + 8);                \
        const float* xr = xsrc + (size_t)((kc) * 32 + bk) * NN + bs * 20;        \
        br[0] = *(const float4*)(xr);                                            \
        br[1] = *(const float4*)(xr + 4);                                        \
        br[2] = *(const float4*)(xr + 8);                                        \
        br[3] = *(const float4*)(xr + 12);                                       \
        br[4] = *(const float4*)(xr + 16);                                       \
    }
#define K2_WRITE(p)                                                              \
    {                                                                            \
        _Float16* Ap = smem + (p) * 10368;                                       \
        _Float16* Bp = Ap + 4608;                                                \
        _Float16* ad = Ap + (t >> 1) * 36 + (t & 1) * 16;                        \
        *(uint2*)(ad + 0) = make_uint2(ar[0].x, ar[0].y);                        \
        *(uint2*)(ad + 4) = make_uint2(ar[0].z, ar[0].w);                        \
        *(uint2*)(ad + 8) = make_uint2(ar[1].x, ar[1].y);                        \
        *(uint2*)(ad + 12) = make_uint2(ar[1].z, ar[1].w);                       \
        _Float16* bd = Bp + bk;                                                  \
        for (int i = 0; i < 5; i++) {                                            \
            int nbase = bs * 20 + 4 * i;                                         \
            bd[(nbase + 0) * 36] = (_Float16)br[i].x;                            \
            bd[(nbase + 1) * 36] = (_Float16)br[i].y;                            \
            bd[(nbase + 2) * 36] = (_Float16)br[i].z;                            \
            bd[(nbase + 3) * 36] = (_Float16)br[i].w;                            \
        }                                                                        \
    }

    K2_LOAD(0);
    K2_WRITE(0);
    __syncthreads();

    for (int kc = 0; kc < 8; ++kc) {
        if (kc < 7) K2_LOAD(kc + 1);
        {
            const _Float16* Ap = smem + (kc & 1) * 10368;
            const _Float16* Bp = Ap + 4608;
#pragma unroll
            for (int kk = 0; kk < 2; kk++) {
                union { f16x8 v; uint2 q[2]; } a;
                const _Float16* ap = Ap + (w * 32 + ln) * 36 + kk * 16 + 8 * h;
                a.q[0] = *(const uint2*)(ap);
                a.q[1] = *(const uint2*)(ap + 4);
#pragma unroll
                for (int j = 0; j < 5; j++) {
                    union { f16x8 v; uint2 q[2]; } bb;
                    const _Float16* bp = Bp + (j * 32 + ln) * 36 + kk * 16 + 8 * h;
                    bb.q[0] = *(const uint2*)(bp);
                    bb.q[1] = *(const uint2*)(bp + 4);
                    acc[j] = __builtin_amdgcn_mfma_f32_32x32x16_f16(a.v, bb.v, acc[j], 0, 0, 0);
                }
            }
        }
        if (kc < 7) {
            K2_WRITE((kc + 1) & 1);
            __syncthreads();
        }
    }

    // epilogue: acc -> gl[128][168] f16, then 2x2 pool + bias -> gT
    __syncthreads();
    _Float16* gl = smem;
#pragma unroll
    for (int j = 0; j < 5; j++)
#pragma unroll
        for (int r = 0; r < 16; r++) {
            int co = w * 32 + (r & 3) + 8 * (r >> 2) + 4 * h;
            gl[co * 168 + j * 32 + ln] = (_Float16)acc[j][r];
        }
    __syncthreads();
    {
        int co = t >> 1, qq = t & 1;
        float bias = gb[co];
        union { _Float16 hv[20]; uint2 u[5]; } ov;
        const _Float16* row = gl + co * 168;
#pragma unroll
        for (int o = 0; o < 20; o++) {
            int wp = qq * 20 + o;
            float a0 = (float)row[2 * wp], a1 = (float)row[2 * wp + 1];
            float a2 = (float)row[80 + 2 * wp], a3 = (float)row[81 + 2 * wp];
            ov.hv[o] = (_Float16)(fmaxf(fmaxf(a0, a1), fmaxf(a2, a3)) + bias);
        }
        _Float16* gT = (_Float16*)(ws + OFF_GT) + (size_t)(b * CIG + co) * NP + nb * 40 + qq * 20;
#pragma unroll
        for (int i = 0; i < 5; i++) *(uint2*)(gT + i * 4) = ov.u[i];
    }
#undef K2_LOAD
#undef K2_WRITE
}

// ---------------- K3: MFMA flash attention, 1-barrier pipelined --------------
// 800 blocks x 512 thr (8 waves). 25 chunks of 64 keys. Pt/gTl/psum double-
// buffered; iteration cc: QK+exp for chunk cc+1 (nxt) interleaved with PV for
// chunk cc (cur), one barrier. ROW PAD = 66 halves = 33 words (ODD) -> every
// LDS access is <=2-way (free); the old 72-half (36-word) pad made all PV
// b128 reads 8-way bank-conflicted.
__global__ __launch_bounds__(512) void k3_attn(float* __restrict__ ws) {
    __shared__ _Float16 Pt[2][128][66];   // 33.8 KB  P[q][k]
    __shared__ _Float16 gTl[2][128][66];  // 33.8 KB  gT[c][k]
    __shared__ float l_run[128];
    __shared__ float psum[2][2][128];
    __shared__ float sum_l[128];

    const int t = threadIdx.x;
    const int w = t >> 6, l = t & 63;
    const int h = l >> 5, q32 = l & 31;
    const int bid = blockIdx.x;
    const int b = bid / 50, nt = bid % 50, n0 = nt * 128;
    const float* theta = ws + OFF_THETA;
    const float* phi   = ws + OFF_PHI;
    const _Float16* gT = (const _Float16*)(ws + OFF_GT) + (size_t)b * CIG * NP;
    const f32x16 z16 = {0.f,0.f,0.f,0.f,0.f,0.f,0.f,0.f,0.f,0.f,0.f,0.f,0.f,0.f,0.f,0.f};

    const int kt = w & 1;          // QK key tile
    const int qt = w >> 1;         // QK query tile (0..3)
    const int ct = w >> 1;         // PV channel tile (0..3)
    const int qp0 = 2 * (w & 1), qp1 = qp0 + 1;

    // theta B-frag (fixed): B[c][q], q = n0 + qt*32 + q32, k-slot c = 8h+j
    f16x8 thB;
#pragma unroll
    for (int j = 0; j < 8; j++) {
        int c = 8 * h + j;
        thB[j] = (c < CI) ? (_Float16)theta[(b * CI + c) * NN + n0 + qt * 32 + q32]
                          : (_Float16)0.f;
    }

    f32x16 acc0 = z16, acc1 = z16;
    if (t < 128) { l_run[t] = 0.f; sum_l[t] = 0.f; }
    const int cst = t >> 2, gp = t & 3;

    // prologue: chunk 0 -> buffers[0]; prefetch phA for chunk 1
    f16x8 phA;
#pragma unroll
    for (int j = 0; j < 8; j++) {
        int c = 8 * h + j;
        phA[j] = (c < CI) ? (_Float16)phi[(b * CI + c) * NP + kt * 32 + q32]
                          : (_Float16)0.f;
    }
    {
        const _Float16* gsrc = gT + (size_t)cst * NP + gp * 16;
        uint4 ga0 = *(const uint4*)(gsrc);
        uint4 ga1 = *(const uint4*)(gsrc + 8);
        f32x16 S = __builtin_amdgcn_mfma_f32_32x32x16_f16(phA, thB, z16, 0, 0, 0);
#pragma unroll
        for (int j = 0; j < 8; j++) {
            int c = 8 * h + j;
            phA[j] = (c < CI) ? (_Float16)phi[(b * CI + c) * NP + 64 + kt * 32 + q32]
                              : (_Float16)0.f;
        }
        float ps = 0.f;
#pragma unroll
        for (int G = 0; G < 4; G++) {
            float e0 = __expf(S[4 * G + 0]);
            float e1 = __expf(S[4 * G + 1]);
            float e2 = __expf(S[4 * G + 2]);
            float e3 = __expf(S[4 * G + 3]);
            ps += (e0 + e1) + (e2 + e3);
            union { _Float16 hv[4]; uint2 u; } pk;
            pk.hv[0] = (_Float16)e0; pk.hv[1] = (_Float16)e1;
            pk.hv[2] = (_Float16)e2; pk.hv[3] = (_Float16)e3;
            *(uint2*)&Pt[0][qt * 32 + q32][kt * 32 + 8 * G + 4 * h] = pk.u;
        }
        ps += __shfl_xor(ps, 32);
        if (l < 32) psum[0][kt][qt * 32 + l] = ps;
        *(uint4*)&gTl[0][cst][gp * 16] = ga0;
        *(uint4*)&gTl[0][cst][gp * 16 + 8] = ga1;
    }
    __syncthreads();

    for (int cc = 0; cc < 25; cc++) {
        const int cur = cc & 1, nxt = cur ^ 1;

        // produce chunk cc+1 into nxt (independent of PV below)
        if (cc < 24) {
            const int m1 = (cc + 1) * 64;
            const _Float16* gsrc = gT + (size_t)cst * NP + m1 + gp * 16;
            uint4 ga0 = *(const uint4*)(gsrc);
            uint4 ga1 = *(const uint4*)(gsrc + 8);

            f32x16 S = __builtin_amdgcn_mfma_f32_32x32x16_f16(phA, thB, z16, 0, 0, 0);

            if (cc < 23) {
                const int m2 = m1 + 64;
#pragma unroll
                for (int j = 0; j < 8; j++) {
                    int c = 8 * h + j;
                    phA[j] = (c < CI) ? (_Float16)phi[(b * CI + c) * NP + m2 + kt * 32 + q32]
                                      : (_Float16)0.f;
                }
            }

            float ps = 0.f;
#pragma unroll
            for (int G = 0; G < 4; G++) {
                float e0 = __expf(S[4 * G + 0]);
                float e1 = __expf(S[4 * G + 1]);
                float e2 = __expf(S[4 * G + 2]);
                float e3 = __expf(S[4 * G + 3]);
                ps += (e0 + e1) + (e2 + e3);
                union { _Float16 hv[4]; uint2 u; } pk;
                pk.hv[0] = (_Float16)e0; pk.hv[1] = (_Float16)e1;
                pk.hv[2] = (_Float16)e2; pk.hv[3] = (_Float16)e3;
                *(uint2*)&Pt[nxt][qt * 32 + q32][kt * 32 + 8 * G + 4 * h] = pk.u;
            }
            ps += __shfl_xor(ps, 32);
            if (l < 32) psum[nxt][kt][qt * 32 + l] = ps;
            *(uint4*)&gTl[nxt][cst][gp * 16] = ga0;
            *(uint4*)&gTl[nxt][cst][gp * 16 + 8] = ga1;
        }

        // consume chunk cc from cur
        if (t < 128) l_run[t] += psum[cur][0][t] + psum[cur][1][t];

        __builtin_amdgcn_s_setprio(1);
#pragma unroll
        for (int kk = 0; kk < 4; kk++) {
            f16x8 gA  = *(const f16x8*)&gTl[cur][ct * 32 + q32][kk * 16 + 8 * h];
            f16x8 pB0 = *(const f16x8*)&Pt[cur][qp0 * 32 + q32][kk * 16 + 8 * h];
            f16x8 pB1 = *(const f16x8*)&Pt[cur][qp1 * 32 + q32][kk * 16 + 8 * h];
            acc0 = __builtin_amdgcn_mfma_f32_32x32x16_f16(gA, pB0, acc0, 0, 0, 0);
            acc1 = __builtin_amdgcn_mfma_f32_32x32x16_f16(gA, pB1, acc1, 0, 0, 0);
        }
        __builtin_amdgcn_s_setprio(0);
        __syncthreads();
    }

    // epilogue: y = acc/l, plus per-channel block sums -> PARTS
    const float inv0 = 1.f / l_run[qp0 * 32 + q32];
    const float inv1 = 1.f / l_run[qp1 * 32 + q32];
    float* y = ws + OFF_Y;
    const int nA = n0 + qp0 * 32 + q32;
    const int nB = n0 + qp1 * 32 + q32;
#pragma unroll
    for (int G = 0; G < 4; G++) {
        int c0 = ct * 32 + 8 * G + 4 * h;
        *(float4*)&y[(size_t)(b * NN + nA) * CIG + c0] =
            make_float4(acc0[4 * G + 0] * inv0, acc0[4 * G + 1] * inv0,
                        acc0[4 * G + 2] * inv0, acc0[4 * G + 3] * inv0);
        *(float4*)&y[(size_t)(b * NN + nB) * CIG + c0] =
            make_float4(acc1[4 * G + 0] * inv1, acc1[4 * G + 1] * inv1,
                        acc1[4 * G + 2] * inv1, acc1[4 * G + 3] * inv1);
    }
#pragma unroll
    for (int G = 0; G < 4; G++)
#pragma unroll
        for (int jj = 0; jj < 4; jj++) {
            float v = acc0[4 * G + jj] * inv0 + acc1[4 * G + jj] * inv1;
            v += __shfl_xor(v, 1);
            v += __shfl_xor(v, 2);
            v += __shfl_xor(v, 4);
            v += __shfl_xor(v, 8);
            v += __shfl_xor(v, 16);
            if (q32 == 0) atomicAdd(&sum_l[ct * 32 + 8 * G + 4 * h + jj], v);
        }
    __syncthreads();
    if (t < 128) ws[OFF_PARTS + t * 800 + bid] = sum_l[t];
}

// ---------------- K3b: reduce PARTS[c][800] -> SUMY[c] -----------------------
__global__ __launch_bounds__(256) void k3b_reduce(float* __restrict__ ws) {
    __shared__ float red[256];
    const int t = threadIdx.x, co = blockIdx.x;
    const float4* src = (const float4*)(ws + OFF_PARTS + co * 800);
    float s = 0.f;
    for (int i = t; i < 200; i += 256) {
        float4 v = src[i];
        s += (v.x + v.y) + (v.z + v.w);
    }
    red[t] = s;
    __syncthreads();
    for (int off = 128; off > 0; off >>= 1) {
        if (t < off) red[t] += red[t + off];
        __syncthreads();
    }
    if (t == 0) ws[OFF_SUMY + co] = red[0];
}

// ---------------- K4: M = Yc^T Yc via MFMA f16 on centered y -----------------
__global__ __launch_bounds__(512) void k4_stats(float* __restrict__ ws) {
    __shared__ _Float16 ys[64][132];
    __shared__ float ybar_l[128];
    const int t = threadIdx.x;
    const int w = t >> 6, l = t & 63, h = l >> 5, ln = l & 31;
    const int bid = blockIdx.x;
    const float* y = ws + OFF_Y;
    if (t < 128) ybar_l[t] = ws[OFF_SUMY + t] * (1.0f / (float)CNT);
    __syncthreads();

    const int tk = w >> 1;
    const int tl0 = 2 * (w & 1), tl1 = tl0 + 1;

    f32x16 acc0 = {0.f,0.f,0.f,0.f,0.f,0.f,0.f,0.f,0.f,0.f,0.f,0.f,0.f,0.f,0.f,0.f};
    f32x16 acc1 = acc0;

    for (int ch = 0; ch < 10; ch++) {
        const float* ysrc = y + ((size_t)bid * 640 + ch * 64) * CIG;
#pragma unroll
        for (int i = 0; i < 4; i++) {
            int f4 = i * 512 + t;
            int n = f4 >> 5, c4 = (f4 & 31) * 4;
            float4 v = *(const float4*)(ysrc + f4 * 4);
            union { _Float16 hv[4]; uint2 u; } p;
            p.hv[0] = (_Float16)(v.x - ybar_l[c4]);
            p.hv[1] = (_Float16)(v.y - ybar_l[c4 + 1]);
            p.hv[2] = (_Float16)(v.z - ybar_l[c4 + 2]);
            p.hv[3] = (_Float16)(v.w - ybar_l[c4 + 3]);
            *(uint2*)&ys[n][c4] = p.u;
        }
        __syncthreads();
#pragma unroll
        for (int kk = 0; kk < 4; kk++) {
            f16x8 av, bv0, bv1;
#pragma unroll
            for (int j = 0; j < 8; j++) {
                int n = kk * 16 + 8 * h + j;
                av[j]  = ys[n][tk * 32 + ln];
                bv0[j] = ys[n][tl0 * 32 + ln];
                bv1[j] = ys[n][tl1 * 32 + ln];
            }
            acc0 = __builtin_amdgcn_mfma_f32_32x32x16_f16(av, bv0, acc0, 0, 0, 0);
            acc1 = __builtin_amdgcn_mfma_f32_32x32x16_f16(av, bv1, acc1, 0, 0, 0);
        }
        __syncthreads();
    }

    float* Myy = ws + OFF_MYY;
#pragma unroll
    for (int r = 0; r < 16; r++) {
        int k = tk * 32 + (r & 3) + 8 * (r >> 2) + 4 * h;
        atomicAdd(&Myy[k * 128 + tl0 * 32 + ln], acc0[r]);
        atomicAdd(&Myy[k * 128 + tl1 * 32 + ln], acc1[r]);
    }
}

// ---------------- K5: BN scale/shift: var = w^T M w / CNT (centered M) -------
__global__ __launch_bounds__(128) void k5_bnparams(const float* __restrict__ Ww,
                                                   const float* __restrict__ Wb,
                                                   const float* __restrict__ gamma,
                                                   const float* __restrict__ beta,
                                                   float* __restrict__ ws) {
    __shared__ float w[128];
    __shared__ float red[128];
    int t = threadIdx.x;
    int co = blockIdx.x;
    w[t] = Ww[co * CIG + t];
    __syncthreads();
    const float inv_cnt = 1.0f / (float)CNT;

    const float* M = ws + OFF_MYY;
    float tk = 0.f;
#pragma unroll
    for (int l4 = 0; l4 < 32; l4++) {
        float4 m4 = *(const float4*)&M[t * 128 + l4 * 4];
        tk += m4.x * w[l4 * 4] + m4.y * w[l4 * 4 + 1] + m4.z * w[l4 * 4 + 2] + m4.w * w[l4 * 4 + 3];
    }
    red[t] = w[t] * tk;
    __syncthreads();
    for (int off = 64; off > 0; off >>= 1) {
        if (t < off) red[t] += red[t + off];
        __syncthreads();
    }
    if (t == 0) {
        float var = red[0] * inv_cnt;
        float a = gamma[co] * rsqrtf(var + 1e-5f);
        ws[OFF_A + co] = a;
        ws[OFF_BC + co] = beta[co];
    }
}

// ---------------- K6: MFMA f16 W-conv on centered y + BN apply + residual ----
__global__ __launch_bounds__(256) void k6_final(const float* __restrict__ x1,
                                                float* __restrict__ out,
                                                const float* __restrict__ ws) {
    __shared__ _Float16 k6s[33792];   // A [128][132] + B [128][132]
    __shared__ float ybar_l[128];
    _Float16* Asm = k6s;
    _Float16* Bsm = k6s + 16896;
    const int t = threadIdx.x;
    const int w = t >> 6, l = t & 63, h = l >> 5, ln = l & 31;
    const int bid = blockIdx.x;
    const int b = bid / 100, rr = bid % 100;
    const int nt = rr >> 1, ch = rr & 1;
    const int n0 = nt * 128, co0 = ch * 128;

    if (t < 128) ybar_l[t] = ws[OFF_SUMY + t] * (1.0f / (float)CNT);
    __syncthreads();

    // A-stage: W f16 [128co][128k] -> [co][132]
    {
        const ushort* wsrc = (const ushort*)(ws + OFF_WW16) + (size_t)co0 * 128;
#pragma unroll
        for (int i = 0; i < 8; i++) {
            int flat = i * 2048 + t * 8;            // halves
            uint4 v = *(const uint4*)(wsrc + flat);
            _Float16* dst = Asm + (flat >> 7) * 132 + (flat & 127);
            *(uint2*)(dst) = make_uint2(v.x, v.y);
            *(uint2*)(dst + 4) = make_uint2(v.z, v.w);
        }
    }
    // B-stage: (y - ybar) fp32 [128n][128k] -> f16 [n][132]
    {
        const float* ysrc = ws + OFF_Y + (size_t)(b * NN + n0) * CIG;
#pragma unroll
        for (int i = 0; i < 16; i++) {
            int flat = i * 1024 + t * 4;            // floats
            int kcol = flat & 127;
            float4 v = *(const float4*)(ysrc + flat);
            union { _Float16 hv[4]; uint2 u; } p;
            p.hv[0] = (_Float16)(v.x - ybar_l[kcol]);
            p.hv[1] = (_Float16)(v.y - ybar_l[kcol + 1]);
            p.hv[2] = (_Float16)(v.z - ybar_l[kcol + 2]);
            p.hv[3] = (_Float16)(v.w - ybar_l[kcol + 3]);
            *(uint2*)(Bsm + (flat >> 7) * 132 + kcol) = p.u;
        }
    }
    __syncthreads();

    f32x16 acc[4];
#pragma unroll
    for (int j = 0; j < 4; j++)
#pragma unroll
        for (int r = 0; r < 16; r++) acc[j][r] = 0.f;

#pragma unroll
    for (int kk = 0; kk < 8; kk++) {
        union { f16x8 v; uint2 q[2]; } a;
        const _Float16* ap = Asm + (w * 32 + ln) * 132 + kk * 16 + 8 * h;
        a.q[0] = *(const uint2*)(ap);
        a.q[1] = *(const uint2*)(ap + 4);
#pragma unroll
        for (int j = 0; j < 4; j++) {
            union { f16x8 v; uint2 q[2]; } bb;
            const _Float16* bp = Bsm + (j * 32 + ln) * 132 + kk * 16 + 8 * h;
            bb.q[0] = *(const uint2*)(bp);
            bb.q[1] = *(const uint2*)(bp + 4);
            acc[j] = __builtin_amdgcn_mfma_f32_32x32x16_f16(a.v, bb.v, acc[j], 0, 0, 0);
        }
    }

    const float* Av = ws + OFF_A;
    const float* Bc = ws + OFF_BC;
#pragma unroll
    for (int r = 0; r < 16; r++) {
        int cor = co0 + w * 32 + (r & 3) + 8 * (r >> 2) + 4 * h;
        float a = Av[cor], bc = Bc[cor];
        size_t base = (size_t)(b * CG + cor) * NN + n0;
#pragma unroll
        for (int j = 0; j < 4; j++) {
            int n = j * 32 + ln;
            out[base + n] = acc[j][r] * a + bc + x1[base + n];
        }
    }
}

extern "C" void kernel_launch(void* const* d_in, const int* in_sizes, int n_in,
                              void* d_out, int out_size, void* d_ws, size_t ws_size,
                              hipStream_t stream) {
    const float* x_c     = (const float*)d_in[0];
    const float* x_1     = (const float*)d_in[1];
    const float* theta_w = (const float*)d_in[2];
    const float* theta_b = (const float*)d_in[3];
    const float* phi_w   = (const float*)d_in[4];
    const float* phi_b   = (const float*)d_in[5];
    const float* g_w     = (const float*)d_in[6];
    const float* g_b     = (const float*)d_in[7];
    const float* W_w     = (const float*)d_in[8];
    const float* W_b     = (const float*)d_in[9];
    const float* gammap  = (const float*)d_in[10];
    const float* betap   = (const float*)d_in[11];
    float* out = (float*)d_out;
    float* ws  = (float*)d_ws;

    k0_prep<<<128, 256, 0, stream>>>(g_w, W_w, ws);
    k1_theta<<<400, 256, 0, stream>>>(x_c, theta_w, theta_b, ws);
    k1_phi<<<100, 256, 0, stream>>>(x_c, phi_w, phi_b, ws);
    k2_convg<<<640, 256, 0, stream>>>(x_1, g_b, ws);
    hipMemsetAsync(ws + OFF_MYY, 0, (128 * 128) * sizeof(float), stream);
    k3_attn<<<800, 512, 0, stream>>>(ws);
    k3b_reduce<<<128, 256, 0, stream>>>(ws);
    k4_stats<<<160, 512, 0, stream>>>(ws);
    k5_bnparams<<<256, 128, 0, stream>>>(W_w, W_b, gammap, betap, ws);
    k6_final<<<1600, 256, 0, stream>>>(x_1, out, ws);
}

// Round 14
// 250.703 us; speedup vs baseline: 1.1245x; 1.1245x over previous
//
#include <hip/hip_runtime.h>
#include <math.h>

#define BB 16
#define CC 20
#define CI 10
#define CG 256
#define CIG 128
#define HH 80
#define WW 80
#define NN 6400
#define HP 40
#define WPD 40
#define NP 1600
#define CNT (BB*NN)   // 102400

// workspace layout (float offsets)
#define OFF_THETA 0
#define OFF_PHI   (OFF_THETA + BB*CI*NN)     // 1,024,000
#define OFF_Y     (OFF_PHI + BB*CI*NP)       // 1,280,000
#define OFF_SUMY  (OFF_Y + BB*NN*CIG)       // 14,387,200
#define OFF_MYY   (OFF_SUMY + 128)
#define OFF_A     (OFF_MYY + 128*128)
#define OFF_BC    (OFF_A + 256)
#define OFF_GW16  (OFF_BC + 256)             // f16: CG*CIG halves, chunk-contig [kc][co][32]
#define OFF_WW16  (OFF_GW16 + CG*CIG/2)      // f16: [co=256][k=128] halves
#define OFF_GT    (OFF_WW16 + CG*CIG/2)      // f16: 16*128*1600 halves
#define OFF_PARTS (OFF_GT + BB*CIG*NP/2)     // fp32: [128][800] per-block channel sums
// total floats: OFF_PARTS + 128*800 = 16,177,792  (~64.7 MB)

typedef _Float16 f16x8 __attribute__((ext_vector_type(8)));
typedef float f32x4 __attribute__((ext_vector_type(4)));
typedef float f32x16 __attribute__((ext_vector_type(16)));

// ---------------- K0: weight prep: gw -> f16 chunk-contig, Ww -> f16 --------
__global__ void k0_prep(const float* __restrict__ gw,
                        const float* __restrict__ ww,
                        float* __restrict__ ws) {
    int idx = blockIdx.x * 256 + threadIdx.x;   // 0..32767
    if (idx < CG * CIG) {
        int co = idx / CG, ci = idx % CG;       // g_w[co][ci], co<128, ci<256
        _Float16* gw16 = (_Float16*)(ws + OFF_GW16);
        gw16[(ci >> 5) * (CIG * 32) + co * 32 + (ci & 31)] = (_Float16)gw[idx];
        _Float16* ww16 = (_Float16*)(ws + OFF_WW16);
        ww16[idx] = (_Float16)ww[idx];          // W_w[co=256][k=128] row-major
    }
}

// ---------------- K1a: theta conv (full res), layout (B, CI, N) --------------
__global__ __launch_bounds__(256) void k1_theta(const float* __restrict__ xc,
                                                const float* __restrict__ tw,
                                                const float* __restrict__ tb,
                                                float* __restrict__ ws) {
    __shared__ float w[CI * CC];
    __shared__ float bia[CI];
    int t = threadIdx.x;
    if (t < CI * CC) w[t] = tw[t];
    if (t < CI) bia[t] = tb[t];
    __syncthreads();
    int idx = blockIdx.x * 256 + t;     // < 102400
    int b = idx / NN, n = idx % NN;
    float acc[CI];
#pragma unroll
    for (int o = 0; o < CI; o++) acc[o] = bia[o];
#pragma unroll
    for (int c = 0; c < CC; c++) {
        float x = xc[(b * CC + c) * NN + n];
#pragma unroll
        for (int o = 0; o < CI; o++) acc[o] += w[o * CC + c] * x;
    }
#pragma unroll
    for (int o = 0; o < CI; o++) ws[OFF_THETA + (b * CI + o) * NN + n] = acc[o];
}

// ---------------- K1b: phi conv + 2x2 maxpool, layout (B, CI, NP) ------------
__global__ __launch_bounds__(256) void k1_phi(const float* __restrict__ xc,
                                              const float* __restrict__ pw,
                                              const float* __restrict__ pb,
                                              float* __restrict__ ws) {
    __shared__ float w[CI * CC];
    __shared__ float bia[CI];
    int t = threadIdx.x;
    if (t < CI * CC) w[t] = pw[t];
    if (t < CI) bia[t] = pb[t];
    __syncthreads();
    int idx = blockIdx.x * 256 + t;    // < 25600
    int b = idx / NP, mp = idx % NP;
    int hp = mp / WPD, wp = mp % WPD;
    float best[CI];
#pragma unroll
    for (int o = 0; o < CI; o++) best[o] = -1e30f;
#pragma unroll
    for (int p = 0; p < 4; p++) {
        int n = (2 * hp + (p >> 1)) * WW + 2 * wp + (p & 1);
        float acc[CI];
#pragma unroll
        for (int o = 0; o < CI; o++) acc[o] = bia[o];
#pragma unroll
        for (int c = 0; c < CC; c++) {
            float x = xc[(b * CC + c) * NN + n];
#pragma unroll
            for (int o = 0; o < CI; o++) acc[o] += w[o * CC + c] * x;
        }
#pragma unroll
        for (int o = 0; o < CI; o++) best[o] = fmaxf(best[o], acc[o]);
    }
#pragma unroll
    for (int o = 0; o < CI; o++) ws[OFF_PHI + (b * CI + o) * NP + mp] = best[o];
}

// ---------------- K2: MFMA f16 g-conv (K=256) + 2x2 maxpool -> gT f16 --------
__global__ __launch_bounds__(256) void k2_convg(const float* __restrict__ x1,
                                                const float* __restrict__ gb,
                                                float* __restrict__ ws) {
    __shared__ _Float16 smem[21760];    // 43.5 KB
    const int t = threadIdx.x;
    const int w = t >> 6, l = t & 63, h = l >> 5, ln = l & 31;
    const int bid = blockIdx.x;
    const int b = bid / 40, nb = bid % 40;
    const int n0 = nb * 160;
    const ushort* gw16 = (const ushort*)(ws + OFF_GW16);
    const float* xsrc = x1 + (size_t)b * CG * NN + n0;

    f32x16 acc[5];
#pragma unroll
    for (int j = 0; j < 5; j++)
#pragma unroll
        for (int r = 0; r < 16; r++) acc[j][r] = 0.f;

    const int bk = t >> 3, bs = t & 7;      // B-stage: k-row, n-seg(20)
    uint4 ar[2];
    float4 br[5];

#define K2_LOAD(kc)                                                              \
    {                                                                            \
        ar[0] = *(const uint4*)(gw16 + (kc) * 4096 + t * 16);                    \
        ar[1] = *(const uint4*)(gw16 + (kc) * 4096 + t * 16 + 8);                \
        const float* xr = xsrc + (size_t)((kc) * 32 + bk) * NN + bs * 20;        \
        br[0] = *(const float4*)(xr);                                            \
        br[1] = *(const float4*)(xr + 4);                                        \
        br[2] = *(const float4*)(xr + 8);                                        \
        br[3] = *(const float4*)(xr + 12);                                       \
        br[4] = *(const float4*)(xr + 16);                                       \
    }
#define K2_WRITE(p)                                                              \
    {                                                                            \
        _Float16* Ap = smem + (p) * 10368;                                       \
        _Float16* Bp = Ap + 4608;                                                \
        _Float16* ad = Ap + (t >> 1) * 36 + (t & 1) * 16;                        \
        *(uint2*)(ad + 0) = make_uint2(ar[0].x, ar[0].y);                        \
        *(uint2*)(ad + 4) = make_uint2(ar[0].z, ar[0].w);                        \
        *(uint2*)(ad + 8) = make_uint2(ar[1].x, ar[1].y);                        \
        *(uint2*)(ad + 12) = make_uint2(ar[1].z, ar[1].w);                       \
        _Float16* bd = Bp + bk;                                                  \
        for (int i = 0; i < 5; i++) {                                            \
            int nbase = bs * 20 + 4 * i;                                         \
            bd[(nbase + 0) * 36] = (_Float16)br[i].x;                            \
            bd[(nbase + 1) * 36] = (_Float16)br[i].y;                            \
            bd[(nbase + 2) * 36] = (_Float16)br[i].z;                            \
            bd[(nbase + 3) * 36] = (_Float16)br[i].w;                            \
        }                                                                        \
    }

    K2_LOAD(0);
    K2_WRITE(0);
    __syncthreads();

    for (int kc = 0; kc < 8; ++kc) {
        if (kc < 7) K2_LOAD(kc + 1);
        {
            const _Float16* Ap = smem + (kc & 1) * 10368;
            const _Float16* Bp = Ap + 4608;
#pragma unroll
            for (int kk = 0; kk < 2; kk++) {
                union { f16x8 v; uint2 q[2]; } a;
                const _Float16* ap = Ap + (w * 32 + ln) * 36 + kk * 16 + 8 * h;
                a.q[0] = *(const uint2*)(ap);
                a.q[1] = *(const uint2*)(ap + 4);
#pragma unroll
                for (int j = 0; j < 5; j++) {
                    union { f16x8 v; uint2 q[2]; } bb;
                    const _Float16* bp = Bp + (j * 32 + ln) * 36 + kk * 16 + 8 * h;
                    bb.q[0] = *(const uint2*)(bp);
                    bb.q[1] = *(const uint2*)(bp + 4);
                    acc[j] = __builtin_amdgcn_mfma_f32_32x32x16_f16(a.v, bb.v, acc[j], 0, 0, 0);
                }
            }
        }
        if (kc < 7) {
            K2_WRITE((kc + 1) & 1);
            __syncthreads();
        }
    }

    // epilogue: acc -> gl[128][168] f16, then 2x2 pool + bias -> gT
    __syncthreads();
    _Float16* gl = smem;
#pragma unroll
    for (int j = 0; j < 5; j++)
#pragma unroll
        for (int r = 0; r < 16; r++) {
            int co = w * 32 + (r & 3) + 8 * (r >> 2) + 4 * h;
            gl[co * 168 + j * 32 + ln] = (_Float16)acc[j][r];
        }
    __syncthreads();
    {
        int co = t >> 1, qq = t & 1;
        float bias = gb[co];
        union { _Float16 hv[20]; uint2 u[5]; } ov;
        const _Float16* row = gl + co * 168;
#pragma unroll
        for (int o = 0; o < 20; o++) {
            int wp = qq * 20 + o;
            float a0 = (float)row[2 * wp], a1 = (float)row[2 * wp + 1];
            float a2 = (float)row[80 + 2 * wp], a3 = (float)row[81 + 2 * wp];
            ov.hv[o] = (_Float16)(fmaxf(fmaxf(a0, a1), fmaxf(a2, a3)) + bias);
        }
        _Float16* gT = (_Float16*)(ws + OFF_GT) + (size_t)(b * CIG + co) * NP + nb * 40 + qq * 20;
#pragma unroll
        for (int i = 0; i < 5; i++) *(uint2*)(gT + i * 4) = ov.u[i];
    }
#undef K2_LOAD
#undef K2_WRITE
}

// ---------------- K3: MFMA flash attention, KVBLK=128, 13 chunks -------------
// 800 blocks x 512 thr (8 waves). Single-buffered Pt/gTl, 2 barriers/chunk.
// Per chunk: each wave does 2 QK MFMAs (kt=w&3, q-tiles 2(w>>2),2(w>>2)+1,
// shared phA), 32 exps (2 indep chains), Pt writes; then PV: ct=w>>1,
// q-tiles 2(w&1),2(w&1)+1, K=128 -> 16 MFMAs, 24 b128 reads.
// Tail chunk 12: kt>=2 tiles invalid -> Pt=0, psum=0, staging addr clamped.
__global__ __launch_bounds__(512) void k3_attn(float* __restrict__ ws) {
    __shared__ _Float16 Pt[128][136];    // 34.8 KB  P[q][k]  (272B rows, 16B-aligned)
    __shared__ _Float16 gTl[128][136];   // 34.8 KB  gT[c][k]
    __shared__ float l_run[128];
    __shared__ float psum[4][128];
    __shared__ float sum_l[128];

    const int t = threadIdx.x;
    const int w = t >> 6, l = t & 63;
    const int h = l >> 5, q32 = l & 31;
    const int bid = blockIdx.x;
    const int b = bid / 50, nt = bid % 50, n0 = nt * 128;
    const float* theta = ws + OFF_THETA;
    const float* phi   = ws + OFF_PHI;
    const _Float16* gT = (const _Float16*)(ws + OFF_GT) + (size_t)b * CIG * NP;
    const f32x16 z16 = {0.f,0.f,0.f,0.f,0.f,0.f,0.f,0.f,0.f,0.f,0.f,0.f,0.f,0.f,0.f,0.f};

    const int kt = w & 3;            // QK key tile (0..3)
    const int qh = w >> 2;           // QK q-tile pair (0..1)
    const int qA = 2 * qh, qB = qA + 1;
    const int ct = w >> 1;           // PV channel tile (0..3)
    const int qp0 = 2 * (w & 1), qp1 = qp0 + 1;

    // theta B-frags (fixed): B[c][q] for q-tiles qA, qB
    f16x8 thB0, thB1;
#pragma unroll
    for (int j = 0; j < 8; j++) {
        int c = 8 * h + j;
        thB0[j] = (c < CI) ? (_Float16)theta[(b * CI + c) * NN + n0 + qA * 32 + q32]
                           : (_Float16)0.f;
        thB1[j] = (c < CI) ? (_Float16)theta[(b * CI + c) * NN + n0 + qB * 32 + q32]
                           : (_Float16)0.f;
    }

    f32x16 acc0 = z16, acc1 = z16;
    if (t < 128) { l_run[t] = 0.f; sum_l[t] = 0.f; }
    const int cst = t >> 2, gp = t & 3;   // gT staging: channel row, 64B quarter

    // prologue: preload phA for chunk 0 (this wave's key tile)
    f16x8 phA;
#pragma unroll
    for (int j = 0; j < 8; j++) {
        int c = 8 * h + j;
        phA[j] = (c < CI) ? (_Float16)phi[(b * CI + c) * NP + kt * 32 + q32]
                          : (_Float16)0.f;
    }
    __syncthreads();

    for (int cc = 0; cc < 13; cc++) {
        const int m0 = cc * 128;
        const bool valid = (m0 + kt * 32) < NP;   // tail: kt>=2 invalid at cc=12

        // issue gT staging loads (clamped in tail; Pt=0 there anyway)
        int scol = m0 + gp * 32;
        if (scol >= NP) scol = 0;
        const _Float16* gsrc = gT + (size_t)cst * NP + scol;
        uint4 ga0 = *(const uint4*)(gsrc);
        uint4 ga1 = *(const uint4*)(gsrc + 8);
        uint4 ga2 = *(const uint4*)(gsrc + 16);
        uint4 ga3 = *(const uint4*)(gsrc + 24);

        // QK: S'[key][q] for (kt, qA) and (kt, qB)
        f32x16 S0, S1;
        if (valid) {
            S0 = __builtin_amdgcn_mfma_f32_32x32x16_f16(phA, thB0, z16, 0, 0, 0);
            S1 = __builtin_amdgcn_mfma_f32_32x32x16_f16(phA, thB1, z16, 0, 0, 0);
        }

        // prefetch next chunk's phA (hidden under exp + PV)
        if (cc < 12) {
            const int m1 = m0 + 128 + kt * 32;
#pragma unroll
            for (int j = 0; j < 8; j++) {
                int c = 8 * h + j;
                phA[j] = (c < CI) ? (_Float16)phi[(b * CI + c) * NP + m1 + q32]
                                  : (_Float16)0.f;
            }
        }

        // exp on D-regs -> Pt; two independent chains
        float ps0 = 0.f, ps1 = 0.f;
        if (valid) {
#pragma unroll
            for (int G = 0; G < 4; G++) {
                float e0 = __expf(S0[4 * G + 0]);
                float e1 = __expf(S0[4 * G + 1]);
                float e2 = __expf(S0[4 * G + 2]);
                float e3 = __expf(S0[4 * G + 3]);
                float f0 = __expf(S1[4 * G + 0]);
                float f1 = __expf(S1[4 * G + 1]);
                float f2 = __expf(S1[4 * G + 2]);
                float f3 = __expf(S1[4 * G + 3]);
                ps0 += (e0 + e1) + (e2 + e3);
                ps1 += (f0 + f1) + (f2 + f3);
                union { _Float16 hv[4]; uint2 u; } pk;
                pk.hv[0] = (_Float16)e0; pk.hv[1] = (_Float16)e1;
                pk.hv[2] = (_Float16)e2; pk.hv[3] = (_Float16)e3;
                *(uint2*)&Pt[qA * 32 + q32][kt * 32 + 8 * G + 4 * h] = pk.u;
                pk.hv[0] = (_Float16)f0; pk.hv[1] = (_Float16)f1;
                pk.hv[2] = (_Float16)f2; pk.hv[3] = (_Float16)f3;
                *(uint2*)&Pt[qB * 32 + q32][kt * 32 + 8 * G + 4 * h] = pk.u;
            }
        } else {
#pragma unroll
            for (int G = 0; G < 4; G++) {
                *(uint2*)&Pt[qA * 32 + q32][kt * 32 + 8 * G + 4 * h] = make_uint2(0, 0);
                *(uint2*)&Pt[qB * 32 + q32][kt * 32 + 8 * G + 4 * h] = make_uint2(0, 0);
            }
        }
        ps0 += __shfl_xor(ps0, 32);
        ps1 += __shfl_xor(ps1, 32);
        if (l < 32) {
            psum[kt][qA * 32 + l] = ps0;
            psum[kt][qB * 32 + l] = ps1;
        }

        // commit gT tile to LDS
        {
            _Float16* gd = &gTl[cst][gp * 32];
            *(uint4*)(gd) = ga0;
            *(uint4*)(gd + 8) = ga1;
            *(uint4*)(gd + 16) = ga2;
            *(uint4*)(gd + 24) = ga3;
        }
        __syncthreads();

        // running per-query denominators
        if (t < 128) l_run[t] += (psum[0][t] + psum[1][t]) + (psum[2][t] + psum[3][t]);

        // PV: acc[32c x 32q] += gT[32c x 128k] . P[128k x 32q], 2 query tiles
        __builtin_amdgcn_s_setprio(1);
#pragma unroll
        for (int kk = 0; kk < 8; kk++) {
            f16x8 gA  = *(const f16x8*)&gTl[ct * 32 + q32][kk * 16 + 8 * h];
            f16x8 pB0 = *(const f16x8*)&Pt[qp0 * 32 + q32][kk * 16 + 8 * h];
            f16x8 pB1 = *(const f16x8*)&Pt[qp1 * 32 + q32][kk * 16 + 8 * h];
            acc0 = __builtin_amdgcn_mfma_f32_32x32x16_f16(gA, pB0, acc0, 0, 0, 0);
            acc1 = __builtin_amdgcn_mfma_f32_32x32x16_f16(gA, pB1, acc1, 0, 0, 0);
        }
        __builtin_amdgcn_s_setprio(0);
        __syncthreads();
    }

    // epilogue: y = acc/l, plus per-channel block sums -> PARTS
    const float inv0 = 1.f / l_run[qp0 * 32 + q32];
    const float inv1 = 1.f / l_run[qp1 * 32 + q32];
    float* y = ws + OFF_Y;
    const int nA = n0 + qp0 * 32 + q32;
    const int nB = n0 + qp1 * 32 + q32;
#pragma unroll
    for (int G = 0; G < 4; G++) {
        int c0 = ct * 32 + 8 * G + 4 * h;
        *(float4*)&y[(size_t)(b * NN + nA) * CIG + c0] =
            make_float4(acc0[4 * G + 0] * inv0, acc0[4 * G + 1] * inv0,
                        acc0[4 * G + 2] * inv0, acc0[4 * G + 3] * inv0);
        *(float4*)&y[(size_t)(b * NN + nB) * CIG + c0] =
            make_float4(acc1[4 * G + 0] * inv1, acc1[4 * G + 1] * inv1,
                        acc1[4 * G + 2] * inv1, acc1[4 * G + 3] * inv1);
    }
#pragma unroll
    for (int G = 0; G < 4; G++)
#pragma unroll
        for (int jj = 0; jj < 4; jj++) {
            float v = acc0[4 * G + jj] * inv0 + acc1[4 * G + jj] * inv1;
            v += __shfl_xor(v, 1);
            v += __shfl_xor(v, 2);
            v += __shfl_xor(v, 4);
            v += __shfl_xor(v, 8);
            v += __shfl_xor(v, 16);
            if (q32 == 0) atomicAdd(&sum_l[ct * 32 + 8 * G + 4 * h + jj], v);
        }
    __syncthreads();
    if (t < 128) ws[OFF_PARTS + t * 800 + bid] = sum_l[t];
}

// ---------------- K3b: reduce PARTS[c][800] -> SUMY[c] -----------------------
__global__ __launch_bounds__(256) void k3b_reduce(float* __restrict__ ws) {
    __shared__ float red[256];
    const int t = threadIdx.x, co = blockIdx.x;
    const float4* src = (const float4*)(ws + OFF_PARTS + co * 800);
    float s = 0.f;
    for (int i = t; i < 200; i += 256) {
        float4 v = src[i];
        s += (v.x + v.y) + (v.z + v.w);
    }
    red[t] = s;
    __syncthreads();
    for (int off = 128; off > 0; off >>= 1) {
        if (t < off) red[t] += red[t + off];
        __syncthreads();
    }
    if (t == 0) ws[OFF_SUMY + co] = red[0];
}

// ---------------- K4: M = Yc^T Yc via MFMA f16 on centered y -----------------
__global__ __launch_bounds__(512) void k4_stats(float* __restrict__ ws) {
    __shared__ _Float16 ys[64][132];
    __shared__ float ybar_l[128];
    const int t = threadIdx.x;
    const int w = t >> 6, l = t & 63, h = l >> 5, ln = l & 31;
    const int bid = blockIdx.x;
    const float* y = ws + OFF_Y;
    if (t < 128) ybar_l[t] = ws[OFF_SUMY + t] * (1.0f / (float)CNT);
    __syncthreads();

    const int tk = w >> 1;
    const int tl0 = 2 * (w & 1), tl1 = tl0 + 1;

    f32x16 acc0 = {0.f,0.f,0.f,0.f,0.f,0.f,0.f,0.f,0.f,0.f,0.f,0.f,0.f,0.f,0.f,0.f};
    f32x16 acc1 = acc0;

    for (int ch = 0; ch < 10; ch++) {
        const float* ysrc = y + ((size_t)bid * 640 + ch * 64) * CIG;
#pragma unroll
        for (int i = 0; i < 4; i++) {
            int f4 = i * 512 + t;
            int n = f4 >> 5, c4 = (f4 & 31) * 4;
            float4 v = *(const float4*)(ysrc + f4 * 4);
            union { _Float16 hv[4]; uint2 u; } p;
            p.hv[0] = (_Float16)(v.x - ybar_l[c4]);
            p.hv[1] = (_Float16)(v.y - ybar_l[c4 + 1]);
            p.hv[2] = (_Float16)(v.z - ybar_l[c4 + 2]);
            p.hv[3] = (_Float16)(v.w - ybar_l[c4 + 3]);
            *(uint2*)&ys[n][c4] = p.u;
        }
        __syncthreads();
#pragma unroll
        for (int kk = 0; kk < 4; kk++) {
            f16x8 av, bv0, bv1;
#pragma unroll
            for (int j = 0; j < 8; j++) {
                int n = kk * 16 + 8 * h + j;
                av[j]  = ys[n][tk * 32 + ln];
                bv0[j] = ys[n][tl0 * 32 + ln];
                bv1[j] = ys[n][tl1 * 32 + ln];
            }
            acc0 = __builtin_amdgcn_mfma_f32_32x32x16_f16(av, bv0, acc0, 0, 0, 0);
            acc1 = __builtin_amdgcn_mfma_f32_32x32x16_f16(av, bv1, acc1, 0, 0, 0);
        }
        __syncthreads();
    }

    float* Myy = ws + OFF_MYY;
#pragma unroll
    for (int r = 0; r < 16; r++) {
        int k = tk * 32 + (r & 3) + 8 * (r >> 2) + 4 * h;
        atomicAdd(&Myy[k * 128 + tl0 * 32 + ln], acc0[r]);
        atomicAdd(&Myy[k * 128 + tl1 * 32 + ln], acc1[r]);
    }
}

// ---------------- K5: BN scale/shift: var = w^T M w / CNT (centered M) -------
__global__ __launch_bounds__(128) void k5_bnparams(const float* __restrict__ Ww,
                                                   const float* __restrict__ Wb,
                                                   const float* __restrict__ gamma,
                                                   const float* __restrict__ beta,
                                                   float* __restrict__ ws) {
    __shared__ float w[128];
    __shared__ float red[128];
    int t = threadIdx.x;
    int co = blockIdx.x;
    w[t] = Ww[co * CIG + t];
    __syncthreads();
    const float inv_cnt = 1.0f / (float)CNT;

    const float* M = ws + OFF_MYY;
    float tk = 0.f;
#pragma unroll
    for (int l4 = 0; l4 < 32; l4++) {
        float4 m4 = *(const float4*)&M[t * 128 + l4 * 4];
        tk += m4.x * w[l4 * 4] + m4.y * w[l4 * 4 + 1] + m4.z * w[l4 * 4 + 2] + m4.w * w[l4 * 4 + 3];
    }
    red[t] = w[t] * tk;
    __syncthreads();
    for (int off = 64; off > 0; off >>= 1) {
        if (t < off) red[t] += red[t + off];
        __syncthreads();
    }
    if (t == 0) {
        float var = red[0] * inv_cnt;
        float a = gamma[co] * rsqrtf(var + 1e-5f);
        ws[OFF_A + co] = a;
        ws[OFF_BC + co] = beta[co];
    }
}

// ---------------- K6: MFMA f16 W-conv on centered y + BN apply + residual ----
__global__ __launch_bounds__(256) void k6_final(const float* __restrict__ x1,
                                                float* __restrict__ out,
                                                const float* __restrict__ ws) {
    __shared__ _Float16 k6s[33792];   // A [128][132] + B [128][132]
    __shared__ float ybar_l[128];
    _Float16* Asm = k6s;
    _Float16* Bsm = k6s + 16896;
    const int t = threadIdx.x;
    const int w = t >> 6, l = t & 63, h = l >> 5, ln = l & 31;
    const int bid = blockIdx.x;
    const int b = bid / 100, rr = bid % 100;
    const int nt = rr >> 1, ch = rr & 1;
    const int n0 = nt * 128, co0 = ch * 128;

    if (t < 128) ybar_l[t] = ws[OFF_SUMY + t] * (1.0f / (float)CNT);
    __syncthreads();

    // A-stage: W f16 [128co][128k] -> [co][132]
    {
        const ushort* wsrc = (const ushort*)(ws + OFF_WW16) + (size_t)co0 * 128;
#pragma unroll
        for (int i = 0; i < 8; i++) {
            int flat = i * 2048 + t * 8;            // halves
            uint4 v = *(const uint4*)(wsrc + flat);
            _Float16* dst = Asm + (flat >> 7) * 132 + (flat & 127);
            *(uint2*)(dst) = make_uint2(v.x, v.y);
            *(uint2*)(dst + 4) = make_uint2(v.z, v.w);
        }
    }
    // B-stage: (y - ybar) fp32 [128n][128k] -> f16 [n][132]
    {
        const float* ysrc = ws + OFF_Y + (size_t)(b * NN + n0) * CIG;
#pragma unroll
        for (int i = 0; i < 16; i++) {
            int flat = i * 1024 + t * 4;            // floats
            int kcol = flat & 127;
            float4 v = *(const float4*)(ysrc + flat);
            union { _Float16 hv[4]; uint2 u; } p;
            p.hv[0] = (_Float16)(v.x - ybar_l[kcol]);
            p.hv[1] = (_Float16)(v.y - ybar_l[kcol + 1]);
            p.hv[2] = (_Float16)(v.z - ybar_l[kcol + 2]);
            p.hv[3] = (_Float16)(v.w - ybar_l[kcol + 3]);
            *(uint2*)(Bsm + (flat >> 7) * 132 + kcol) = p.u;
        }
    }
    __syncthreads();

    f32x16 acc[4];
#pragma unroll
    for (int j = 0; j < 4; j++)
#pragma unroll
        for (int r = 0; r < 16; r++) acc[j][r] = 0.f;

#pragma unroll
    for (int kk = 0; kk < 8; kk++) {
        union { f16x8 v; uint2 q[2]; } a;
        const _Float16* ap = Asm + (w * 32 + ln) * 132 + kk * 16 + 8 * h;
        a.q[0] = *(const uint2*)(ap);
        a.q[1] = *(const uint2*)(ap + 4);
#pragma unroll
        for (int j = 0; j < 4; j++) {
            union { f16x8 v; uint2 q[2]; } bb;
            const _Float16* bp = Bsm + (j * 32 + ln) * 132 + kk * 16 + 8 * h;
            bb.q[0] = *(const uint2*)(bp);
            bb.q[1] = *(const uint2*)(bp + 4);
            acc[j] = __builtin_amdgcn_mfma_f32_32x32x16_f16(a.v, bb.v, acc[j], 0, 0, 0);
        }
    }

    const float* Av = ws + OFF_A;
    const float* Bc = ws + OFF_BC;
#pragma unroll
    for (int r = 0; r < 16; r++) {
        int cor = co0 + w * 32 + (r & 3) + 8 * (r >> 2) + 4 * h;
        float a = Av[cor], bc = Bc[cor];
        size_t base = (size_t)(b * CG + cor) * NN + n0;
#pragma unroll
        for (int j = 0; j < 4; j++) {
            int n = j * 32 + ln;
            out[base + n] = acc[j][r] * a + bc + x1[base + n];
        }
    }
}

extern "C" void kernel_launch(void* const* d_in, const int* in_sizes, int n_in,
                              void* d_out, int out_size, void* d_ws, size_t ws_size,
                              hipStream_t stream) {
    const float* x_c     = (const float*)d_in[0];
    const float* x_1     = (const float*)d_in[1];
    const float* theta_w = (const float*)d_in[2];
    const float* theta_b = (const float*)d_in[3];
    const float* phi_w   = (const float*)d_in[4];
    const float* phi_b   = (const float*)d_in[5];
    const float* g_w     = (const float*)d_in[6];
    const float* g_b     = (const float*)d_in[7];
    const float* W_w     = (const float*)d_in[8];
    const float* W_b     = (const float*)d_in[9];
    const float* gammap  = (const float*)d_in[10];
    const float* betap   = (const float*)d_in[11];
    float* out = (float*)d_out;
    float* ws  = (float*)d_ws;

    k0_prep<<<128, 256, 0, stream>>>(g_w, W_w, ws);
    k1_theta<<<400, 256, 0, stream>>>(x_c, theta_w, theta_b, ws);
    k1_phi<<<100, 256, 0, stream>>>(x_c, phi_w, phi_b, ws);
    k2_convg<<<640, 256, 0, stream>>>(x_1, g_b, ws);
    hipMemsetAsync(ws + OFF_MYY, 0, (128 * 128) * sizeof(float), stream);
    k3_attn<<<800, 512, 0, stream>>>(ws);
    k3b_reduce<<<128, 256, 0, stream>>>(ws);
    k4_stats<<<160, 512, 0, stream>>>(ws);
    k5_bnparams<<<256, 128, 0, stream>>>(W_w, W_b, gammap, betap, ws);
    k6_final<<<1600, 256, 0, stream>>>(x_1, out, ws);
}